// Round 11
// baseline (82.337 us; speedup 1.0000x reference)
//
#include <hip/hip_runtime.h>
#include <hip/hip_bf16.h>
#include <cstdint>

static constexpr int H  = 2048;
static constexpr int W  = 2048;
static constexpr int NG = 65536;
static constexpr int R  = 16;          // patch = 33x33
static constexpr int TS = 32;          // tile size
static constexpr int TX = W / TS;      // 64
static constexpr int NT = TX * (H / TS);  // 4096 tiles
static constexpr int MAXPG = 192;      // slots/tile (mean 64; huge margin)
static constexpr size_t HW = (size_t)H * W;

typedef float v2f __attribute__((ext_vector_type(2)));

__device__ __forceinline__ uint32_t bf16bits(float x) {
    return (uint32_t)__bfloat16_as_ushort(__float2bfloat16(x));
}

// Kernel A: derived params, materialized as 32B records per overlapped tile.
// A=(mx, my, K/l11, dwK=K/l22)  B=(ddK=K*l21/(l11*l22), wr, wi, uu2=exp2(-4*dwK^2))
// K = sqrt(0.5*log2 e) folds exp(-0.5 x^2) -> exp2(-(Kx)^2).
__global__ __launch_bounds__(256) void gf_bin(
    const float* __restrict__ means,
    const float* __restrict__ chol,
    const float* __restrict__ weights,
    uint32_t* __restrict__ cnt,
    float4* __restrict__ lst)
{
    const int n = blockIdx.x * 256 + threadIdx.x;
    if (n >= NG) return;

    const float2 mn = ((const float2*)means)[n];
    const float2 wt = ((const float2*)weights)[n];
    const float mx = mn.x, my = mn.y;
    const float c0  = chol[3 * n + 0];
    const float l21 = chol[3 * n + 1];
    const float c2  = chol[3 * n + 2];

    // softplus(x) = max(x,0) + log1p(exp(-|x|)); short series (z small here)
    auto softp = [](float x) {
        const float z  = __expf(-fabsf(x));
        const float lp = z - 0.5f * z * z + 0.33333333f * z * z * z;
        return fmaxf(x, 0.0f) + lp;
    };
    const float l11 = 0.5f + softp(c0);
    const float l22 = 0.5f + softp(c2);

    constexpr float KK = 0.84932180028801905f;   // sqrt(0.5*log2(e))
    const float iaK = KK / l11;
    const float dwK = KK / l22;
    const float ddK = KK * l21 / (l11 * l22);
    const float uu2 = exp2f(-4.0f * dwK * dwK);

    const float4 A = make_float4(mx, my, iaK, dwK);
    const float4 B = make_float4(ddK, wt.x, wt.y, uu2);

    const int tlx = (int)floorf(mx) - R;
    const int tly = (int)floorf(my) - R;
    const int x0 = max(tlx, 0), x1 = min(tlx + 2 * R, W - 1);
    const int y0 = max(tly, 0), y1 = min(tly + 2 * R, H - 1);
    const int tx0 = x0 >> 5, tx1 = x1 >> 5;
    const int ty0 = y0 >> 5, ty1 = y1 >> 5;

    for (int yy = ty0; yy <= ty1; ++yy)
        for (int xx = tx0; xx <= tx1; ++xx) {
            const int t = yy * TX + xx;
            const uint32_t slot = atomicAdd(&cnt[t], 1u);
            if (slot < MAXPG) {
                const size_t o = ((size_t)t * MAXPG + slot) * 2;
                lst[o + 0] = A;
                lst[o + 1] = B;
            }
        }
}

// Kernel B: 256-thread block = 2 tiles; each tile processed by TWO waves
// (16 rows each). Block cooperatively stages both record lists into LDS;
// hot loop reads records via broadcast ds_read_b128. Per lane: col = lane&31,
// rows row0..row0+7 in registers (packed (re,im) v2f, v_pk_fma_f32).
// Row recurrence: G=(g_r,g_{r+1}); G*=T; T*=U. No predicates (tail <= ~6e-4).
__global__ __launch_bounds__(256, 8) void gf_tiles(
    const float4* __restrict__ lst,
    const uint32_t* __restrict__ cnt,
    const float* __restrict__ init_re,
    const float* __restrict__ init_im,
    const float* __restrict__ rs,
    uint32_t* __restrict__ out)
{
    __shared__ float4 sp[2][2 * MAXPG];          // 12 KB

    const int t0 = blockIdx.x * 2;
    const int m0 = min((int)cnt[t0 + 0], MAXPG);
    const int m1 = min((int)cnt[t0 + 1], MAXPG);

    for (int i = threadIdx.x; i < 2 * m0; i += 256)
        sp[0][i] = lst[(size_t)(t0 + 0) * (2 * MAXPG) + i];
    for (int i = threadIdx.x; i < 2 * m1; i += 256)
        sp[1][i] = lst[(size_t)(t0 + 1) * (2 * MAXPG) + i];
    __syncthreads();

    const int wid  = threadIdx.x >> 6;           // 0..3
    const int lane = threadIdx.x & 63;
    const int tsel = wid >> 1;                   // tile within block
    const int half = wid & 1;                    // row half (0..1)
    const int tile = t0 + tsel;
    const int tx = tile & (TX - 1), ty = tile >> 6;
    const int gx0 = tx * TS, gy0 = ty * TS;
    const int col  = lane & 31;
    const int row0 = half * 16 + (lane >> 5) * 8;   // 0/8/16/24
    const int gx = gx0 + col;
    const float fx  = (float)gx;
    const float fy0 = (float)(gy0 + row0);

    v2f acc[8];
#pragma unroll
    for (int it = 0; it < 8; ++it) acc[it] = (v2f)(0.0f);

    const int m = tsel ? m1 : m0;
    const float4* __restrict__ sl = sp[tsel];

    for (int j = 0; j < m; ++j) {
        const float4 A = sl[2 * j + 0];
        const float4 B = sl[2 * j + 1];

        const float dx  = fx  - A.x;
        const float dy0 = fy0 - A.y;
        const float u1  = A.z * dx;
        const float b   = -(u1 * u1);
        const float w0  = fmaf(A.w, dy0, -(B.x * dx));
        const float w1  = w0 + A.w;
        const float q0  = fmaf(-w0, w0, b);
        const float q1  = fmaf(-w1, w1, b);
        const float g0  = exp2f(q0);
        const float g1  = exp2f(q1);
        const float tau0 = exp2f(-4.0f * A.w * w1);   // g_{r+2}/g_r at r=row0
        const float uu4  = B.w * B.w;

        v2f G = { g0, g1 };
        v2f T = { tau0, tau0 * B.w };
        const v2f U  = { uu4, uu4 };
        const v2f wg = { B.y, B.z };

#pragma unroll
        for (int i2 = 0; i2 < 4; ++i2) {
            acc[2 * i2 + 0] = __builtin_elementwise_fma(wg, G.xx, acc[2 * i2 + 0]);
            acc[2 * i2 + 1] = __builtin_elementwise_fma(wg, G.yy, acc[2 * i2 + 1]);
            G *= T;
            T *= U;
        }
    }

    const float s = rs[0];
#pragma unroll
    for (int it = 0; it < 8; ++it) {
        const size_t pix = (size_t)(gy0 + row0 + it) * W + gx;
        out[pix] = bf16bits(fmaf(s, acc[it].x, init_re[pix]))
                 | (bf16bits(fmaf(s, acc[it].y, init_im[pix])) << 16);
    }
}

extern "C" void kernel_launch(void* const* d_in, const int* in_sizes, int n_in,
                              void* d_out, int out_size, void* d_ws, size_t ws_size,
                              hipStream_t stream) {
    // Inputs arrive NAME-SORTED: chol, init_im, init_re, means, residual_scale,
    // weights (verified round 6). Classify by element count.
    const float* means   = nullptr;
    const float* chol    = nullptr;
    const float* weights = nullptr;
    const float* planeA  = nullptr;   // init_im (first H*W)
    const float* planeB  = nullptr;   // init_re (second H*W)
    const float* rs      = nullptr;

    int nSmall = 0, nBig = 0;
    for (int i = 0; i < n_in; ++i) {
        const int sz = in_sizes[i];
        const float* p = (const float*)d_in[i];
        if      (sz == 3 * NG)  chol = p;
        else if (sz == 1)       rs = p;
        else if (sz == 2 * NG)  { if (nSmall++ == 0) means = p; else weights = p; }
        else if (sz == (int)HW) { if (nBig++   == 0) planeA = p; else planeB = p; }
    }
    if (!means || !chol || !weights || !planeA || !planeB || !rs) return;

    const float* init_im = planeA;
    const float* init_re = planeB;

    // ws layout: cnt (16KB) | lst (NT*MAXPG*32B = 25.2MB)
    uint8_t* w8 = (uint8_t*)d_ws;
    uint32_t* cnt = (uint32_t*)w8;
    float4*   lst = (float4*)(w8 + 16 * 1024);

    hipMemsetAsync(cnt, 0, NT * sizeof(uint32_t), stream);

    gf_bin<<<NG / 256, 256, 0, stream>>>(means, chol, weights, cnt, lst);
    gf_tiles<<<NT / 2, 256, 0, stream>>>(lst, cnt, init_re, init_im, rs,
                                         (uint32_t*)d_out);
}

// Round 12
// 73.918 us; speedup vs baseline: 1.1139x; 1.1139x over previous
//
#include <hip/hip_runtime.h>
#include <hip/hip_bf16.h>
#include <cstdint>

static constexpr int H  = 2048;
static constexpr int W  = 2048;
static constexpr int NG = 65536;
static constexpr int R  = 16;          // patch = 33x33
static constexpr int TS = 32;          // tile size
static constexpr int TX = W / TS;      // 64
static constexpr int NT = TX * (H / TS);  // 4096 tiles
static constexpr int MAXPG = 128;      // slots/tile (mean 64, sigma 8 -> 8 sigma margin)
static constexpr size_t HW = (size_t)H * W;

typedef float v2f __attribute__((ext_vector_type(2)));

__device__ __forceinline__ uint32_t bf16bits(float x) {
    return (uint32_t)__bfloat16_as_ushort(__float2bfloat16(x));
}

// Kernel A: contiguous per-gaussian param table (2MB, coalesced) + 4B index
// per overlapped tile (<=2x2). A=(mx,my,K/l11,dwK=K/l22)
// B=(ddK=K*l21/(l11*l22), wr, wi, uu2=exp2(-4*dwK^2)); K=sqrt(0.5*log2 e).
__global__ __launch_bounds__(256) void gf_bin(
    const float* __restrict__ means,
    const float* __restrict__ chol,
    const float* __restrict__ weights,
    uint32_t* __restrict__ cnt,
    uint32_t* __restrict__ lst,
    float4* __restrict__ par)
{
    const int n = blockIdx.x * 256 + threadIdx.x;
    if (n >= NG) return;

    const float2 mn = ((const float2*)means)[n];
    const float2 wt = ((const float2*)weights)[n];
    const float mx = mn.x, my = mn.y;
    const float c0  = chol[3 * n + 0];
    const float l21 = chol[3 * n + 1];
    const float c2  = chol[3 * n + 2];

    // softplus(x) = max(x,0) + log1p(exp(-|x|)); short series (z small here)
    auto softp = [](float x) {
        const float z  = __expf(-fabsf(x));
        const float lp = z - 0.5f * z * z + 0.33333333f * z * z * z;
        return fmaxf(x, 0.0f) + lp;
    };
    const float l11 = 0.5f + softp(c0);
    const float l22 = 0.5f + softp(c2);

    constexpr float KK = 0.84932180028801905f;   // sqrt(0.5*log2(e))
    const float iaK = KK / l11;
    const float dwK = KK / l22;
    const float ddK = KK * l21 / (l11 * l22);
    const float uu2 = exp2f(-4.0f * dwK * dwK);

    par[2 * n + 0] = make_float4(mx, my, iaK, dwK);
    par[2 * n + 1] = make_float4(ddK, wt.x, wt.y, uu2);

    const int tlx = (int)floorf(mx) - R;
    const int tly = (int)floorf(my) - R;
    const int x0 = max(tlx, 0), x1 = min(tlx + 2 * R, W - 1);
    const int y0 = max(tly, 0), y1 = min(tly + 2 * R, H - 1);
    const int tx0 = x0 >> 5, tx1 = x1 >> 5;
    const int ty0 = y0 >> 5, ty1 = y1 >> 5;

    for (int yy = ty0; yy <= ty1; ++yy)
        for (int xx = tx0; xx <= tx1; ++xx) {
            const int t = yy * TX + xx;
            const uint32_t slot = atomicAdd(&cnt[t], 1u);
            if (slot < MAXPG) lst[(size_t)t * MAXPG + slot] = (uint32_t)n;
        }
}

// Kernel B: 256-thread block = 4 waves = 4 tiles (one wave per 32x32 tile).
// Staging: gather each tile's records into LDS via its index list (16KB).
// Lane = col (lane&31) x row-half (lane>>5): rows row0..row0+15 in registers.
// Packed accumulators: aR[i]={re_2i,re_2i+1}, aI likewise; broadcast regs
// WR/WI/U built once per pair -> inner loop = 4 v_pk instr per 2 rows,
// no swizzles. Row recurrence G*=T, T*=U (validated rounds 9-11).
// No predicates: out-of-box tails <= ~6e-4 (absmax 0.0625, 3 rounds).
__global__ __launch_bounds__(256, 6) void gf_tiles(
    const float4* __restrict__ par,
    const uint32_t* __restrict__ cnt,
    const uint32_t* __restrict__ lst,
    const float* __restrict__ init_re,
    const float* __restrict__ init_im,
    const float* __restrict__ rs,
    uint32_t* __restrict__ out)
{
    __shared__ float4 sp[4][2 * MAXPG];          // 16 KB
    __shared__ int sm[4];

    const int t0 = blockIdx.x * 4;
    if (threadIdx.x < 4) sm[threadIdx.x] = min((int)cnt[t0 + threadIdx.x], MAXPG);
    __syncthreads();

#pragma unroll
    for (int t = 0; t < 4; ++t) {
        const int mt = sm[t];
        for (int i = threadIdx.x; i < mt; i += 256) {
            const uint32_t n = lst[(size_t)(t0 + t) * MAXPG + i];
            sp[t][2 * i + 0] = par[2 * (size_t)n + 0];
            sp[t][2 * i + 1] = par[2 * (size_t)n + 1];
        }
    }
    __syncthreads();

    const int wid  = threadIdx.x >> 6;           // wave = tile select
    const int lane = threadIdx.x & 63;
    const int tile = t0 + wid;
    const int tx = tile & (TX - 1), ty = tile >> 6;
    const int gx0 = tx * TS, gy0 = ty * TS;
    const int col  = lane & 31;
    const int row0 = (lane >> 5) * 16;           // 0 or 16
    const int gx = gx0 + col;
    const float fx  = (float)gx;
    const float fy0 = (float)(gy0 + row0);

    v2f aR[8], aI[8];
#pragma unroll
    for (int i = 0; i < 8; ++i) { aR[i] = (v2f)(0.0f); aI[i] = (v2f)(0.0f); }

    const int m = sm[wid];
    const float4* __restrict__ sl = sp[wid];

    for (int j = 0; j < m; ++j) {
        const float4 A = sl[2 * j + 0];
        const float4 B = sl[2 * j + 1];

        const float dx  = fx  - A.x;
        const float dy0 = fy0 - A.y;
        const float u1  = A.z * dx;
        const float nb  = u1 * u1;
        const float w0  = fmaf(A.w, dy0, -(B.x * dx));
        const float w1  = w0 + A.w;
        const float q0  = -fmaf(w0, w0, nb);
        const float q1  = -fmaf(w1, w1, nb);
        const float g0  = exp2f(q0);
        const float g1  = exp2f(q1);
        const float tau0 = exp2f(-4.0f * A.w * w1);   // g_{r+2}/g_r at r=row0
        const float tau1 = tau0 * B.w;
        const float uu4  = B.w * B.w;

        v2f G = { g0, g1 };
        v2f T = { tau0, tau1 };
        const v2f U  = (v2f)(uu4);
        const v2f WR = (v2f)(B.y);
        const v2f WI = (v2f)(B.z);

#pragma unroll
        for (int i = 0; i < 8; ++i) {
            aR[i] = __builtin_elementwise_fma(WR, G, aR[i]);
            aI[i] = __builtin_elementwise_fma(WI, G, aI[i]);
            G *= T;
            T *= U;
        }
    }

    const float s = rs[0];
#pragma unroll
    for (int i = 0; i < 8; ++i) {
        const size_t pix0 = (size_t)(gy0 + row0 + 2 * i) * W + gx;
        const size_t pix1 = pix0 + W;
        out[pix0] = bf16bits(fmaf(s, aR[i].x, init_re[pix0]))
                  | (bf16bits(fmaf(s, aI[i].x, init_im[pix0])) << 16);
        out[pix1] = bf16bits(fmaf(s, aR[i].y, init_re[pix1]))
                  | (bf16bits(fmaf(s, aI[i].y, init_im[pix1])) << 16);
    }
}

extern "C" void kernel_launch(void* const* d_in, const int* in_sizes, int n_in,
                              void* d_out, int out_size, void* d_ws, size_t ws_size,
                              hipStream_t stream) {
    // Inputs arrive NAME-SORTED: chol, init_im, init_re, means, residual_scale,
    // weights (verified round 6). Classify by element count.
    const float* means   = nullptr;
    const float* chol    = nullptr;
    const float* weights = nullptr;
    const float* planeA  = nullptr;   // init_im (first H*W)
    const float* planeB  = nullptr;   // init_re (second H*W)
    const float* rs      = nullptr;

    int nSmall = 0, nBig = 0;
    for (int i = 0; i < n_in; ++i) {
        const int sz = in_sizes[i];
        const float* p = (const float*)d_in[i];
        if      (sz == 3 * NG)  chol = p;
        else if (sz == 1)       rs = p;
        else if (sz == 2 * NG)  { if (nSmall++ == 0) means = p; else weights = p; }
        else if (sz == (int)HW) { if (nBig++   == 0) planeA = p; else planeB = p; }
    }
    if (!means || !chol || !weights || !planeA || !planeB || !rs) return;

    const float* init_im = planeA;
    const float* init_re = planeB;

    // ws layout: cnt (16KB) | lst (NT*MAXPG*4B = 2MB) | par (NG*32B = 2MB)
    uint8_t* w8 = (uint8_t*)d_ws;
    uint32_t* cnt = (uint32_t*)w8;
    uint32_t* lst = (uint32_t*)(w8 + 16 * 1024);
    float4*   par = (float4*)(w8 + 16 * 1024 + (size_t)NT * MAXPG * sizeof(uint32_t));

    hipMemsetAsync(cnt, 0, NT * sizeof(uint32_t), stream);

    gf_bin<<<NG / 256, 256, 0, stream>>>(means, chol, weights, cnt, lst, par);
    gf_tiles<<<NT / 4, 256, 0, stream>>>(par, cnt, lst, init_re, init_im, rs,
                                         (uint32_t*)d_out);
}